// Round 1
// baseline (1101.257 us; speedup 1.0000x reference)
//
#include <hip/hip_runtime.h>
#include <hip/hip_bf16.h>
#include <math.h>

#define NN 20000
#define EE 320000
#define IND 128
#define HH 6
#define CC 64
#define HCC 384
#define NCC 16
#define NGG 64

// ---------------- utility kernels ----------------

__global__ void zero_init_kernel(int* counts, float* pooled, int n, int np) {
    int t = blockIdx.x * blockDim.x + threadIdx.x;
    if (t < n) counts[t] = 0;
    if (t < np) pooled[t] = 0.0f;
}

__global__ void count_kernel(const int* __restrict__ ei, int* __restrict__ counts, int E) {
    int t = blockIdx.x * blockDim.x + threadIdx.x;
    if (t < E) atomicAdd(&counts[ei[E + t]], 1);
}

// single-block exclusive scan of (counts[i]+1), writes offsets[0..n] and cursor
__global__ void scan_kernel(const int* __restrict__ counts, int* __restrict__ offsets,
                            int* __restrict__ cursor, int n) {
    __shared__ int part[1024];
    int t = threadIdx.x;
    int per = (n + 1023) / 1024;
    int base = t * per;
    int sum = 0;
    for (int j = 0; j < per; ++j) {
        int idx = base + j;
        if (idx < n) sum += counts[idx] + 1;
    }
    part[t] = sum;
    __syncthreads();
    for (int off = 1; off < 1024; off <<= 1) {
        int v = (t >= off) ? part[t - off] : 0;
        __syncthreads();
        part[t] += v;
        __syncthreads();
    }
    int run = (t == 0) ? 0 : part[t - 1];
    for (int j = 0; j < per; ++j) {
        int idx = base + j;
        if (idx < n) {
            int deg = counts[idx] + 1;
            offsets[idx] = run;
            cursor[idx] = run;
            run += deg;
        }
    }
    if (t == 1023) offsets[n] = part[1023];
}

__global__ void fill_kernel(const int* __restrict__ ei, int* __restrict__ cursor,
                            int* __restrict__ srcs, int E, int n) {
    int t = blockIdx.x * blockDim.x + threadIdx.x;
    if (t < E) {
        int s = ei[t];
        int d = ei[E + t];
        int slot = atomicAdd(&cursor[d], 1);
        srcs[slot] = s;
    } else if (t < E + n) {
        int i = t - E;
        int slot = atomicAdd(&cursor[i], 1);
        srcs[slot] = i;
    }
}

// ---------------- GEMM: C[M,Nn] = A[M,K] @ B[K,Nn] + bias ----------------
// block 256 (16x16 threads), 64x64 tile, BK=16, 4x4 per thread
__global__ __launch_bounds__(256) void gemm_bias_kernel(
    const float* __restrict__ A, const float* __restrict__ B,
    const float* __restrict__ bias, float* __restrict__ Cm,
    int M, int Nn, int K)
{
    __shared__ float As[16][64];
    __shared__ float Bs[16][64];
    int t = threadIdx.x;
    int tx = t & 15, ty = t >> 4;
    int m0 = blockIdx.x * 64, n0 = blockIdx.y * 64;

    int la_r = t >> 2;            // 0..63  (A tile row)
    int la_k = (t & 3) << 2;      // 0,4,8,12 (A tile k, float4)
    int lb_k = t >> 4;            // 0..15  (B tile k row)
    int lb_n = (t & 15) << 2;     // 0..60  (B tile col, float4)

    float acc[4][4];
#pragma unroll
    for (int i = 0; i < 4; ++i)
#pragma unroll
        for (int j = 0; j < 4; ++j) acc[i][j] = 0.0f;

    for (int k0 = 0; k0 < K; k0 += 16) {
        int am = m0 + la_r;
        float4 av;
        if (am < M) av = *(const float4*)&A[(size_t)am * K + k0 + la_k];
        else        av = make_float4(0.f, 0.f, 0.f, 0.f);
        As[la_k + 0][la_r] = av.x;
        As[la_k + 1][la_r] = av.y;
        As[la_k + 2][la_r] = av.z;
        As[la_k + 3][la_r] = av.w;

        float4 bv = *(const float4*)&B[(size_t)(k0 + lb_k) * Nn + n0 + lb_n];
        *(float4*)&Bs[lb_k][lb_n] = bv;
        __syncthreads();

#pragma unroll
        for (int k = 0; k < 16; ++k) {
            float a[4], b[4];
#pragma unroll
            for (int j = 0; j < 4; ++j) a[j] = As[k][ty * 4 + j];
#pragma unroll
            for (int j = 0; j < 4; ++j) b[j] = Bs[k][tx * 4 + j];
#pragma unroll
            for (int i = 0; i < 4; ++i)
#pragma unroll
                for (int j = 0; j < 4; ++j) acc[i][j] += a[i] * b[j];
        }
        __syncthreads();
    }

#pragma unroll
    for (int i = 0; i < 4; ++i) {
        int m = m0 + ty * 4 + i;
        if (m < M) {
#pragma unroll
            for (int j = 0; j < 4; ++j) {
                int nn = n0 + tx * 4 + j;
                float v = acc[i][j] + (bias ? bias[nn] : 0.0f);
                Cm[(size_t)m * Nn + nn] = v;
            }
        }
    }
}

// ---------------- GATv2 per-node kernel (one wave per node) ----------------
// lane = channel (C=64). H heads kept in registers.
template <int H>
__global__ __launch_bounds__(256) void gat_kernel(
    const float* __restrict__ xl, const float* __restrict__ xr,
    const float* __restrict__ att, const float* __restrict__ bias,
    const float* __restrict__ res, float* __restrict__ out,
    const int* __restrict__ offsets, const int* __restrict__ srcs,
    float* __restrict__ ebuf, int n)
{
    const int HC = H * 64;
    int wid = (blockIdx.x * blockDim.x + threadIdx.x) >> 6;
    int lane = threadIdx.x & 63;
    if (wid >= n) return;
    int i = wid;
    int beg = offsets[i], end = offsets[i + 1];

    float xr_i[H], att_l[H], m[H], s[H];
#pragma unroll
    for (int h = 0; h < H; ++h) {
        xr_i[h] = xr[(size_t)i * HC + h * 64 + lane];
        att_l[h] = att[h * 64 + lane];
        m[h] = -INFINITY;
        s[h] = 0.0f;
    }

    // pass 1: logits + online (max, sum)
    for (int p = beg; p < end; ++p) {
        int sj = srcs[p];
        float eh[H];
#pragma unroll
        for (int h = 0; h < H; ++h) {
            float v = xl[(size_t)sj * HC + h * 64 + lane] + xr_i[h];
            v = v > 0.0f ? v : 0.2f * v;
            eh[h] = v * att_l[h];
        }
#pragma unroll
        for (int off = 32; off > 0; off >>= 1) {
#pragma unroll
            for (int h = 0; h < H; ++h) eh[h] += __shfl_xor(eh[h], off, 64);
        }
#pragma unroll
        for (int h = 0; h < H; ++h) {
            float e = eh[h];
            if (e > m[h]) {
                s[h] *= __expf(m[h] - e);
                m[h] = e;
            }
            s[h] += __expf(e - m[h]);
        }
        if (lane == 0) {
#pragma unroll
            for (int h = 0; h < H; ++h) ebuf[(size_t)p * H + h] = eh[h];
        }
    }

    float inv[H], acc[H];
#pragma unroll
    for (int h = 0; h < H; ++h) {
        inv[h] = 1.0f / (s[h] + 1e-16f);
        acc[h] = 0.0f;
    }

    // pass 2: weighted aggregation
    for (int p = beg; p < end; ++p) {
        int sj = srcs[p];
#pragma unroll
        for (int h = 0; h < H; ++h) {
            float e = ebuf[(size_t)p * H + h];
            float w = __expf(e - m[h]) * inv[h];
            acc[h] += xl[(size_t)sj * HC + h * 64 + lane] * w;
        }
    }

    // epilogue: +bias, elu, +residual
#pragma unroll
    for (int h = 0; h < H; ++h) {
        float v = acc[h] + bias[h * 64 + lane];
        v = v > 0.0f ? v : expm1f(v);
        out[(size_t)i * HC + h * 64 + lane] = v + res[(size_t)i * HC + h * 64 + lane];
    }
}

// ---------------- pooling (batch is sorted) ----------------
__global__ void pool_kernel(const float* __restrict__ h, const int* __restrict__ batch,
                            float* __restrict__ pooled, int n) {
    const int CHUNK = 128;
    int start = blockIdx.x * CHUNK;
    int lane = threadIdx.x;  // 64
    if (start >= n) return;
    int end = start + CHUNK;
    if (end > n) end = n;
    float acc = 0.0f;
    int cur = batch[start];
    for (int i = start; i < end; ++i) {
        int g = batch[i];
        if (g != cur) {
            atomicAdd(&pooled[cur * 64 + lane], acc);
            acc = 0.0f;
            cur = g;
        }
        acc += h[(size_t)i * 64 + lane];
    }
    atomicAdd(&pooled[cur * 64 + lane], acc);
}

// ---------------- dense head ----------------
__global__ void head_kernel(const float* __restrict__ pooled,
                            const float* __restrict__ d1w, const float* __restrict__ d1b,
                            const float* __restrict__ bng, const float* __restrict__ bnb,
                            const float* __restrict__ bnm, const float* __restrict__ bnv,
                            const float* __restrict__ d2w, const float* __restrict__ d2b,
                            float* __restrict__ zout) {
    __shared__ float z1[64 * 64];
    int t = threadIdx.x;  // 256
    for (int idx = t; idx < 64 * 64; idx += 256) {
        int r = idx >> 6, c = idx & 63;
        float acc = d1b[c];
        for (int k = 0; k < 64; ++k) acc += pooled[r * 64 + k] * d1w[k * 64 + c];
        acc = (acc - bnm[c]) / sqrtf(bnv[c] + 1e-5f) * bng[c] + bnb[c];
        z1[idx] = acc > 0.0f ? acc : 0.0f;
    }
    __syncthreads();
    for (int idx = t; idx < 64 * NCC; idx += 256) {
        int r = idx >> 4, c = idx & 15;
        float acc = d2b[c];
        for (int k = 0; k < 64; ++k) acc += z1[r * 64 + k] * d2w[k * NCC + c];
        zout[idx] = acc;
    }
}

// ---------------- launcher ----------------

extern "C" void kernel_launch(void* const* d_in, const int* in_sizes, int n_in,
                              void* d_out, int out_size, void* d_ws, size_t ws_size,
                              hipStream_t stream) {
    const int N = NN, E = EE, H = HH, C = CC, HC = HCC, NG = NGG;
    const int EN = E + N;

    const float* x     = (const float*)d_in[0];
    const int*   ei    = (const int*)d_in[1];
    const int*   batch = (const int*)d_in[2];
    const float* inp_w = (const float*)d_in[3];
    const float* inp_b = (const float*)d_in[4];
    const float* l0_wl = (const float*)d_in[5];
    const float* l0_bl = (const float*)d_in[6];
    const float* l0_wr = (const float*)d_in[7];
    const float* l0_br = (const float*)d_in[8];
    const float* l0_att = (const float*)d_in[9];
    const float* l0_bias = (const float*)d_in[10];
    const float* l1_wl = (const float*)d_in[11];
    const float* l1_bl = (const float*)d_in[12];
    const float* l1_wr = (const float*)d_in[13];
    const float* l1_br = (const float*)d_in[14];
    const float* l1_att = (const float*)d_in[15];
    const float* l1_bias = (const float*)d_in[16];
    const float* l2_wl = (const float*)d_in[17];
    const float* l2_bl = (const float*)d_in[18];
    const float* l2_wr = (const float*)d_in[19];
    const float* l2_br = (const float*)d_in[20];
    const float* l2_att = (const float*)d_in[21];
    const float* l2_bias = (const float*)d_in[22];
    const float* res_w = (const float*)d_in[23];
    const float* d1_w = (const float*)d_in[24];
    const float* d1_b = (const float*)d_in[25];
    const float* bn_g = (const float*)d_in[26];
    const float* bn_b = (const float*)d_in[27];
    const float* bn_m = (const float*)d_in[28];
    const float* bn_v = (const float*)d_in[29];
    const float* d2_w = (const float*)d_in[30];
    const float* d2_b = (const float*)d_in[31];

    float* out = (float*)d_out;

    // workspace partition (256B aligned chunks)
    char* ws = (char*)d_ws;
    size_t off = 0;
    auto alloc = [&](size_t bytes) -> void* {
        void* p = ws + off;
        off += (bytes + 255) & ~(size_t)255;
        return p;
    };
    float* bufH   = (float*)alloc((size_t)N * HC * 4);
    float* bufXL  = (float*)alloc((size_t)N * HC * 4);
    float* bufXR  = (float*)alloc((size_t)N * HC * 4);
    float* bufRes = (float*)alloc((size_t)N * C * 4);
    float* ebuf   = (float*)alloc((size_t)EN * H * 4);
    int*   counts = (int*)alloc((size_t)N * 4);
    int*   cursor = (int*)alloc((size_t)N * 4);
    int*   offsets= (int*)alloc((size_t)(N + 1) * 4);
    int*   srcs   = (int*)alloc((size_t)EN * 4);
    float* pooled = (float*)alloc((size_t)NG * C * 4);

    // CSR build
    int zi_n = N > NG * C ? N : NG * C;
    zero_init_kernel<<<(zi_n + 255) / 256, 256, 0, stream>>>(counts, pooled, N, NG * C);
    count_kernel<<<(E + 255) / 256, 256, 0, stream>>>(ei, counts, E);
    scan_kernel<<<1, 1024, 0, stream>>>(counts, offsets, cursor, N);
    fill_kernel<<<(EN + 255) / 256, 256, 0, stream>>>(ei, cursor, srcs, E, N);

    dim3 blk(256);
    dim3 gHC((N + 63) / 64, HC / 64);
    dim3 gC((N + 63) / 64, C / 64);
    int gatBlocks = (N * 64 + 255) / 256;

    // x_res = x @ inp_w + inp_b
    gemm_bias_kernel<<<gHC, blk, 0, stream>>>(x, inp_w, inp_b, bufH, N, HC, IND);
    // layer 0
    gemm_bias_kernel<<<gHC, blk, 0, stream>>>(x, l0_wl, l0_bl, bufXL, N, HC, IND);
    gemm_bias_kernel<<<gHC, blk, 0, stream>>>(x, l0_wr, l0_br, bufXR, N, HC, IND);
    gat_kernel<HH><<<gatBlocks, blk, 0, stream>>>(bufXL, bufXR, l0_att, l0_bias,
                                                  bufH, bufH, offsets, srcs, ebuf, N);
    // layer 1
    gemm_bias_kernel<<<gHC, blk, 0, stream>>>(bufH, l1_wl, l1_bl, bufXL, N, HC, HC);
    gemm_bias_kernel<<<gHC, blk, 0, stream>>>(bufH, l1_wr, l1_br, bufXR, N, HC, HC);
    gat_kernel<HH><<<gatBlocks, blk, 0, stream>>>(bufXL, bufXR, l1_att, l1_bias,
                                                  bufH, bufH, offsets, srcs, ebuf, N);
    // layer 2 (H=1, C out) + residual projection
    gemm_bias_kernel<<<gC, blk, 0, stream>>>(bufH, l2_wl, l2_bl, bufXL, N, C, HC);
    gemm_bias_kernel<<<gC, blk, 0, stream>>>(bufH, l2_wr, l2_br, bufXR, N, C, HC);
    gemm_bias_kernel<<<gC, blk, 0, stream>>>(bufH, res_w, nullptr, bufRes, N, C, HC);
    gat_kernel<1><<<gatBlocks, blk, 0, stream>>>(bufXL, bufXR, l2_att, l2_bias,
                                                 bufRes, out, offsets, srcs, ebuf, N);
    // pooling + head
    pool_kernel<<<(N + 127) / 128, 64, 0, stream>>>(out, batch, pooled, N);
    head_kernel<<<1, 256, 0, stream>>>(pooled, d1_w, d1_b, bn_g, bn_b, bn_m, bn_v,
                                       d2_w, d2_b, out + (size_t)N * C);
}

// Round 2
// 817.781 us; speedup vs baseline: 1.3466x; 1.3466x over previous
//
#include <hip/hip_runtime.h>
#include <hip/hip_bf16.h>
#include <math.h>

#define NN 20000
#define EE 320000
#define IND 128
#define HH 6
#define CC 64
#define HCC 384
#define NCC 16
#define NGG 64

typedef __bf16 bf16x8 __attribute__((ext_vector_type(8)));
typedef float f32x4 __attribute__((ext_vector_type(4)));
typedef unsigned short ushort_t;
typedef unsigned int uint_t;

__device__ inline ushort_t f2bf(float f) {
    union { float f; uint_t u; } x; x.f = f;
    uint_t r = (x.u + 0x7FFF + ((x.u >> 16) & 1)) >> 16;
    return (ushort_t)r;
}
__device__ inline float bf2f(ushort_t h) {
    union { uint_t u; float f; } x; x.u = ((uint_t)h) << 16; return x.f;
}

// ---------------- utility kernels ----------------

__global__ void zero_init_kernel(int* counts, float* pooled, int n, int np) {
    int t = blockIdx.x * blockDim.x + threadIdx.x;
    if (t < n) counts[t] = 0;
    if (t < np) pooled[t] = 0.0f;
}

__global__ void count_kernel(const int* __restrict__ ei, int* __restrict__ counts, int E) {
    int t = blockIdx.x * blockDim.x + threadIdx.x;
    if (t < E) atomicAdd(&counts[ei[E + t]], 1);
}

__global__ void scan_kernel(const int* __restrict__ counts, int* __restrict__ offsets,
                            int* __restrict__ cursor, int n) {
    __shared__ int part[1024];
    int t = threadIdx.x;
    int per = (n + 1023) / 1024;
    int base = t * per;
    int sum = 0;
    for (int j = 0; j < per; ++j) {
        int idx = base + j;
        if (idx < n) sum += counts[idx] + 1;
    }
    part[t] = sum;
    __syncthreads();
    for (int off = 1; off < 1024; off <<= 1) {
        int v = (t >= off) ? part[t - off] : 0;
        __syncthreads();
        part[t] += v;
        __syncthreads();
    }
    int run = (t == 0) ? 0 : part[t - 1];
    for (int j = 0; j < per; ++j) {
        int idx = base + j;
        if (idx < n) {
            int deg = counts[idx] + 1;
            offsets[idx] = run;
            cursor[idx] = run;
            run += deg;
        }
    }
    if (t == 1023) offsets[n] = part[1023];
}

__global__ void fill_kernel(const int* __restrict__ ei, int* __restrict__ cursor,
                            int* __restrict__ srcs, int E, int n) {
    int t = blockIdx.x * blockDim.x + threadIdx.x;
    if (t < E) {
        int s = ei[t];
        int d = ei[E + t];
        int slot = atomicAdd(&cursor[d], 1);
        srcs[slot] = s;
    } else if (t < E + n) {
        int i = t - E;
        int slot = atomicAdd(&cursor[i], 1);
        srcs[slot] = i;
    }
}

// ---------------- weight/input prep: fp32 -> bf16, concat ----------------
#define W_INP (IND * HCC)
#define W_CAT0 (IND * 2 * HCC)
#define W_CAT1 (HCC * 2 * HCC)
#define W_CAT2 (HCC * 2 * CC)
#define W_RES (HCC * CC)
#define XB_N (NN * IND)
#define PREP_TOTAL (W_INP + W_CAT0 + W_CAT1 + W_CAT2 + W_RES + XB_N + 2 * HCC + 2 * HCC + 2 * CC)

__global__ void prep_kernel(const float* __restrict__ x, const float* __restrict__ inp_w,
    const float* __restrict__ l0wl, const float* __restrict__ l0wr,
    const float* __restrict__ l1wl, const float* __restrict__ l1wr,
    const float* __restrict__ l2wl, const float* __restrict__ l2wr,
    const float* __restrict__ resw,
    const float* __restrict__ l0bl, const float* __restrict__ l0br,
    const float* __restrict__ l1bl, const float* __restrict__ l1br,
    const float* __restrict__ l2bl, const float* __restrict__ l2br,
    ushort_t* wInp, ushort_t* wCat0, ushort_t* wCat1, ushort_t* wCat2, ushort_t* wRes,
    ushort_t* xb, float* bc0, float* bc1, float* bc2)
{
    int i = blockIdx.x * blockDim.x + threadIdx.x;
    if (i >= PREP_TOTAL) return;
    if (i < W_INP) { wInp[i] = f2bf(inp_w[i]); return; }
    i -= W_INP;
    if (i < W_CAT0) {
        int row = i / (2 * HCC); int col = i - row * (2 * HCC);
        float v = col < HCC ? l0wl[row * HCC + col] : l0wr[row * HCC + col - HCC];
        wCat0[i] = f2bf(v); return;
    }
    i -= W_CAT0;
    if (i < W_CAT1) {
        int row = i / (2 * HCC); int col = i - row * (2 * HCC);
        float v = col < HCC ? l1wl[row * HCC + col] : l1wr[row * HCC + col - HCC];
        wCat1[i] = f2bf(v); return;
    }
    i -= W_CAT1;
    if (i < W_CAT2) {
        int row = i / (2 * CC); int col = i - row * (2 * CC);
        float v = col < CC ? l2wl[row * CC + col] : l2wr[row * CC + col - CC];
        wCat2[i] = f2bf(v); return;
    }
    i -= W_CAT2;
    if (i < W_RES) { wRes[i] = f2bf(resw[i]); return; }
    i -= W_RES;
    if (i < XB_N) { xb[i] = f2bf(x[i]); return; }
    i -= XB_N;
    if (i < 2 * HCC) { bc0[i] = i < HCC ? l0bl[i] : l0br[i - HCC]; return; }
    i -= 2 * HCC;
    if (i < 2 * HCC) { bc1[i] = i < HCC ? l1bl[i] : l1br[i - HCC]; return; }
    i -= 2 * HCC;
    if (i < 2 * CC) { bc2[i] = i < CC ? l2bl[i] : l2br[i - CC]; return; }
}

// ---------------- bf16 MFMA GEMM: C[M,N] = A[M,K]@B[K,N] + bias ----------------
// block 256 = 4 waves; tile 128(M) x 64(N), BK=32. LDS padded stride 40 elems.
__global__ __launch_bounds__(256) void gemm_mfma(
    const ushort_t* __restrict__ A, const ushort_t* __restrict__ B,
    const float* __restrict__ bias, float* __restrict__ Cf,
    ushort_t* __restrict__ Cb, int M, int N, int K)
{
    __shared__ ushort_t As[128 * 40];
    __shared__ ushort_t Bs[64 * 40];
    int t = threadIdx.x;
    int w = t >> 6, L = t & 63;
    int m0 = blockIdx.x * 128, n0 = blockIdx.y * 64;
    int q = L >> 4, r16 = L & 15;

    f32x4 acc[2][4];
#pragma unroll
    for (int a = 0; a < 2; ++a)
#pragma unroll
        for (int b = 0; b < 4; ++b) acc[a][b] = (f32x4){0.f, 0.f, 0.f, 0.f};

    int sa_r = t >> 2;           // 0..63
    int sa_k = (t & 3) * 8;      // 0,8,16,24
    int sb_k = t >> 3;           // 0..31
    int sb_n = (t & 7) * 8;      // 0..56
    int rot = (sb_n >> 3) & 7;

    for (int k0 = 0; k0 < K; k0 += 32) {
        __syncthreads();
        // stage A (128x32), 2 rows per thread, zero-fill beyond M
#pragma unroll
        for (int rr0 = 0; rr0 < 2; ++rr0) {
            int rr = sa_r + rr0 * 64;
            int gm = m0 + rr;
            uint4 v = make_uint4(0u, 0u, 0u, 0u);
            if (gm < M) v = *(const uint4*)(A + (size_t)gm * K + k0 + sa_k);
            *(uint4*)(&As[rr * 40 + sa_k]) = v;
        }
        // stage B transposed (Bs[n][k]), staggered writes to avoid bank conflicts
        {
            uint4 v = *(const uint4*)(B + (size_t)(k0 + sb_k) * N + n0 + sb_n);
            ushort_t e[8];
            *(uint4*)e = v;
#pragma unroll
            for (int i = 0; i < 8; ++i) {
                int ii = (i + rot) & 7;
                Bs[(sb_n + ii) * 40 + sb_k] = e[ii];
            }
        }
        __syncthreads();
        // compute: wave w covers rows [w*32, w*32+32)
        bf16x8 a0 = *(const bf16x8*)&As[(w * 32 + r16) * 40 + q * 8];
        bf16x8 a1 = *(const bf16x8*)&As[(w * 32 + 16 + r16) * 40 + q * 8];
#pragma unroll
        for (int ct = 0; ct < 4; ++ct) {
            bf16x8 b = *(const bf16x8*)&Bs[(ct * 16 + r16) * 40 + q * 8];
            acc[0][ct] = __builtin_amdgcn_mfma_f32_16x16x32_bf16(a0, b, acc[0][ct], 0, 0, 0);
            acc[1][ct] = __builtin_amdgcn_mfma_f32_16x16x32_bf16(a1, b, acc[1][ct], 0, 0, 0);
        }
    }
    // epilogue: D[row=(L>>4)*4+r][col=L&15] per 16x16 tile
#pragma unroll
    for (int rt = 0; rt < 2; ++rt) {
#pragma unroll
        for (int ct = 0; ct < 4; ++ct) {
            int col = n0 + ct * 16 + r16;
            float bv = bias ? bias[col] : 0.0f;
#pragma unroll
            for (int rr = 0; rr < 4; ++rr) {
                int row = m0 + w * 32 + rt * 16 + q * 4 + rr;
                if (row < M) {
                    float v = acc[rt][ct][rr] + bv;
                    if (Cf) Cf[(size_t)row * N + col] = v;
                    if (Cb) Cb[(size_t)row * N + col] = f2bf(v);
                }
            }
        }
    }
}

// ---------------- GATv2 per-node kernel (one wave per node, bf16 gather) ----------------
template <int H>
__global__ __launch_bounds__(256) void gat_kernel(
    const ushort_t* __restrict__ xl, const ushort_t* __restrict__ xr, int strideX,
    const float* __restrict__ att, const float* __restrict__ bias,
    const float* __restrict__ res, int strideRes,
    float* __restrict__ out, int strideOut, ushort_t* __restrict__ outB,
    const int* __restrict__ offsets, const int* __restrict__ srcs,
    float* __restrict__ ebuf, int n)
{
    int wid = (blockIdx.x * blockDim.x + threadIdx.x) >> 6;
    int lane = threadIdx.x & 63;
    if (wid >= n) return;
    int i = wid;
    int beg = offsets[i], end = offsets[i + 1];

    float xr_i[H], att_l[H], m[H], s[H];
#pragma unroll
    for (int h = 0; h < H; ++h) {
        xr_i[h] = bf2f(xr[(size_t)i * strideX + h * 64 + lane]);
        att_l[h] = att[h * 64 + lane];
        m[h] = -INFINITY;
        s[h] = 0.0f;
    }

    // pass 1: logits + online (max, sum)
    for (int p = beg; p < end; ++p) {
        int sj = srcs[p];
        float eh[H];
#pragma unroll
        for (int h = 0; h < H; ++h) {
            float v = bf2f(xl[(size_t)sj * strideX + h * 64 + lane]) + xr_i[h];
            v = v > 0.0f ? v : 0.2f * v;
            eh[h] = v * att_l[h];
        }
#pragma unroll
        for (int off = 32; off > 0; off >>= 1) {
#pragma unroll
            for (int h = 0; h < H; ++h) eh[h] += __shfl_xor(eh[h], off, 64);
        }
#pragma unroll
        for (int h = 0; h < H; ++h) {
            float e = eh[h];
            if (e > m[h]) {
                s[h] *= __expf(m[h] - e);
                m[h] = e;
            }
            s[h] += __expf(e - m[h]);
        }
        if (lane == 0) {
#pragma unroll
            for (int h = 0; h < H; ++h) ebuf[(size_t)p * H + h] = eh[h];
        }
    }

    float inv[H], acc[H];
#pragma unroll
    for (int h = 0; h < H; ++h) {
        inv[h] = 1.0f / (s[h] + 1e-16f);
        acc[h] = 0.0f;
    }

    // pass 2: weighted aggregation
    for (int p = beg; p < end; ++p) {
        int sj = srcs[p];
#pragma unroll
        for (int h = 0; h < H; ++h) {
            float e = ebuf[(size_t)p * H + h];
            float wgt = __expf(e - m[h]) * inv[h];
            acc[h] += bf2f(xl[(size_t)sj * strideX + h * 64 + lane]) * wgt;
        }
    }

    // epilogue: +bias, elu, +residual; fp32 out + optional bf16 shadow
#pragma unroll
    for (int h = 0; h < H; ++h) {
        float v = acc[h] + bias[h * 64 + lane];
        v = v > 0.0f ? v : expm1f(v);
        v += res[(size_t)i * strideRes + h * 64 + lane];
        out[(size_t)i * strideOut + h * 64 + lane] = v;
        if (outB) outB[(size_t)i * strideOut + h * 64 + lane] = f2bf(v);
    }
}

// ---------------- pooling (batch is sorted) ----------------
__global__ void pool_kernel(const float* __restrict__ h, const int* __restrict__ batch,
                            float* __restrict__ pooled, int n) {
    const int CHUNK = 128;
    int start = blockIdx.x * CHUNK;
    int lane = threadIdx.x;  // 64
    if (start >= n) return;
    int end = start + CHUNK;
    if (end > n) end = n;
    float acc = 0.0f;
    int cur = batch[start];
    for (int i = start; i < end; ++i) {
        int g = batch[i];
        if (g != cur) {
            atomicAdd(&pooled[cur * 64 + lane], acc);
            acc = 0.0f;
            cur = g;
        }
        acc += h[(size_t)i * 64 + lane];
    }
    atomicAdd(&pooled[cur * 64 + lane], acc);
}

// ---------------- dense head ----------------
__global__ void head_kernel(const float* __restrict__ pooled,
                            const float* __restrict__ d1w, const float* __restrict__ d1b,
                            const float* __restrict__ bng, const float* __restrict__ bnb,
                            const float* __restrict__ bnm, const float* __restrict__ bnv,
                            const float* __restrict__ d2w, const float* __restrict__ d2b,
                            float* __restrict__ zout) {
    __shared__ float z1[64 * 64];
    int t = threadIdx.x;  // 256
    for (int idx = t; idx < 64 * 64; idx += 256) {
        int r = idx >> 6, c = idx & 63;
        float acc = d1b[c];
        for (int k = 0; k < 64; ++k) acc += pooled[r * 64 + k] * d1w[k * 64 + c];
        acc = (acc - bnm[c]) / sqrtf(bnv[c] + 1e-5f) * bng[c] + bnb[c];
        z1[idx] = acc > 0.0f ? acc : 0.0f;
    }
    __syncthreads();
    for (int idx = t; idx < 64 * NCC; idx += 256) {
        int r = idx >> 4, c = idx & 15;
        float acc = d2b[c];
        for (int k = 0; k < 64; ++k) acc += z1[r * 64 + k] * d2w[k * NCC + c];
        zout[idx] = acc;
    }
}

// ---------------- launcher ----------------

extern "C" void kernel_launch(void* const* d_in, const int* in_sizes, int n_in,
                              void* d_out, int out_size, void* d_ws, size_t ws_size,
                              hipStream_t stream) {
    const int N = NN, E = EE, C = CC, HC = HCC, NG = NGG;
    const int EN = E + N;

    const float* x     = (const float*)d_in[0];
    const int*   ei    = (const int*)d_in[1];
    const int*   batch = (const int*)d_in[2];
    const float* inp_w = (const float*)d_in[3];
    const float* inp_b = (const float*)d_in[4];
    const float* l0_wl = (const float*)d_in[5];
    const float* l0_bl = (const float*)d_in[6];
    const float* l0_wr = (const float*)d_in[7];
    const float* l0_br = (const float*)d_in[8];
    const float* l0_att = (const float*)d_in[9];
    const float* l0_bias = (const float*)d_in[10];
    const float* l1_wl = (const float*)d_in[11];
    const float* l1_bl = (const float*)d_in[12];
    const float* l1_wr = (const float*)d_in[13];
    const float* l1_br = (const float*)d_in[14];
    const float* l1_att = (const float*)d_in[15];
    const float* l1_bias = (const float*)d_in[16];
    const float* l2_wl = (const float*)d_in[17];
    const float* l2_bl = (const float*)d_in[18];
    const float* l2_wr = (const float*)d_in[19];
    const float* l2_br = (const float*)d_in[20];
    const float* l2_att = (const float*)d_in[21];
    const float* l2_bias = (const float*)d_in[22];
    const float* res_w = (const float*)d_in[23];
    const float* d1_w = (const float*)d_in[24];
    const float* d1_b = (const float*)d_in[25];
    const float* bn_g = (const float*)d_in[26];
    const float* bn_b = (const float*)d_in[27];
    const float* bn_m = (const float*)d_in[28];
    const float* bn_v = (const float*)d_in[29];
    const float* d2_w = (const float*)d_in[30];
    const float* d2_b = (const float*)d_in[31];

    float* out = (float*)d_out;

    char* ws = (char*)d_ws;
    size_t off = 0;
    auto alloc = [&](size_t bytes) -> void* {
        void* p = ws + off;
        off += (bytes + 255) & ~(size_t)255;
        return p;
    };
    float*    bufH    = (float*)alloc((size_t)N * HC * 4);        // fp32 h (res/out)
    ushort_t* bufH_b  = (ushort_t*)alloc((size_t)N * HC * 2);     // bf16 shadow of h
    ushort_t* cat01_b = (ushort_t*)alloc((size_t)N * 768 * 2);    // xl|xr (layer0, then layer1)
    float*    bufXres = (float*)alloc((size_t)N * HC * 4);        // x_res fp32 (layer0 res)
    ushort_t* cat2_b  = (ushort_t*)alloc((size_t)N * 128 * 2);    // layer2 xl|xr
    float*    bufRes  = (float*)alloc((size_t)N * C * 4);         // layer2 res fp32
    ushort_t* xb      = (ushort_t*)alloc((size_t)N * IND * 2);    // x bf16
    ushort_t* wInp    = (ushort_t*)alloc((size_t)W_INP * 2);
    ushort_t* wCat0   = (ushort_t*)alloc((size_t)W_CAT0 * 2);
    ushort_t* wCat1   = (ushort_t*)alloc((size_t)W_CAT1 * 2);
    ushort_t* wCat2   = (ushort_t*)alloc((size_t)W_CAT2 * 2);
    ushort_t* wRes    = (ushort_t*)alloc((size_t)W_RES * 2);
    float*    bc0     = (float*)alloc((size_t)2 * HC * 4);
    float*    bc1     = (float*)alloc((size_t)2 * HC * 4);
    float*    bc2     = (float*)alloc((size_t)2 * C * 4);
    float*    ebuf    = (float*)alloc((size_t)EN * HH * 4);
    int*      counts  = (int*)alloc((size_t)N * 4);
    int*      cursor  = (int*)alloc((size_t)N * 4);
    int*      offsets = (int*)alloc((size_t)(N + 1) * 4);
    int*      srcs    = (int*)alloc((size_t)EN * 4);
    float*    pooled  = (float*)alloc((size_t)NG * C * 4);

    // CSR build + weight prep
    int zi_n = N > NG * C ? N : NG * C;
    zero_init_kernel<<<(zi_n + 255) / 256, 256, 0, stream>>>(counts, pooled, N, NG * C);
    count_kernel<<<(E + 255) / 256, 256, 0, stream>>>(ei, counts, E);
    scan_kernel<<<1, 1024, 0, stream>>>(counts, offsets, cursor, N);
    fill_kernel<<<(EN + 255) / 256, 256, 0, stream>>>(ei, cursor, srcs, E, N);
    prep_kernel<<<(PREP_TOTAL + 255) / 256, 256, 0, stream>>>(
        x, inp_w, l0_wl, l0_wr, l1_wl, l1_wr, l2_wl, l2_wr, res_w,
        l0_bl, l0_br, l1_bl, l1_br, l2_bl, l2_br,
        wInp, wCat0, wCat1, wCat2, wRes, xb, bc0, bc1, bc2);

    dim3 blk(256);
    int mtiles = (N + 127) / 128;
    int gatBlocks = (N * 64 + 255) / 256;

    // x_res = x @ inp_w + inp_b  (fp32 out)
    gemm_mfma<<<dim3(mtiles, HC / 64), blk, 0, stream>>>(xb, wInp, inp_b, bufXres, nullptr, N, HC, IND);
    // layer 0 xl|xr (bf16 out)
    gemm_mfma<<<dim3(mtiles, 768 / 64), blk, 0, stream>>>(xb, wCat0, bc0, nullptr, cat01_b, N, 768, IND);
    gat_kernel<HH><<<gatBlocks, blk, 0, stream>>>(cat01_b, cat01_b + HC, 768, l0_att, l0_bias,
                                                  bufXres, HC, bufH, HC, bufH_b,
                                                  offsets, srcs, ebuf, N);
    // layer 1
    gemm_mfma<<<dim3(mtiles, 768 / 64), blk, 0, stream>>>(bufH_b, wCat1, bc1, nullptr, cat01_b, N, 768, HC);
    gat_kernel<HH><<<gatBlocks, blk, 0, stream>>>(cat01_b, cat01_b + HC, 768, l1_att, l1_bias,
                                                  bufH, HC, bufH, HC, bufH_b,
                                                  offsets, srcs, ebuf, N);
    // layer 2 (H=1) + residual projection
    gemm_mfma<<<dim3(mtiles, 128 / 64), blk, 0, stream>>>(bufH_b, wCat2, bc2, nullptr, cat2_b, N, 128, HC);
    gemm_mfma<<<dim3(mtiles, 64 / 64), blk, 0, stream>>>(bufH_b, wRes, nullptr, bufRes, nullptr, N, C, HC);
    gat_kernel<1><<<gatBlocks, blk, 0, stream>>>(cat2_b, cat2_b + C, 128, l2_att, l2_bias,
                                                 bufRes, C, out, C, nullptr,
                                                 offsets, srcs, ebuf, N);
    // pooling + head
    pool_kernel<<<(N + 127) / 128, 64, 0, stream>>>(out, batch, pooled, N);
    head_kernel<<<1, 256, 0, stream>>>(pooled, d1_w, d1_b, bn_g, bn_b, bn_m, bn_v,
                                       d2_w, d2_b, out + (size_t)N * C);
}

// Round 3
// 654.523 us; speedup vs baseline: 1.6825x; 1.2494x over previous
//
#include <hip/hip_runtime.h>
#include <hip/hip_bf16.h>
#include <math.h>

#define NN 20000
#define EE 320000
#define IND 128
#define HH 6
#define CC 64
#define HCC 384
#define NCC 16
#define NGG 64

typedef __bf16 bf16x8 __attribute__((ext_vector_type(8)));
typedef float f32x4 __attribute__((ext_vector_type(4)));
typedef unsigned short ushort_t;
typedef unsigned int uint_t;

__device__ inline ushort_t f2bf(float f) {
    union { float f; uint_t u; } x; x.f = f;
    uint_t r = (x.u + 0x7FFF + ((x.u >> 16) & 1)) >> 16;
    return (ushort_t)r;
}
__device__ inline float bf2f(ushort_t h) {
    union { uint_t u; float f; } x; x.u = ((uint_t)h) << 16; return x.f;
}
// 8 packed bf16 (uint4) -> 8 floats
__device__ inline void bf8cvt(uint4 v, float* f) {
    union { uint_t u; float x; } a;
    a.u = v.x << 16;          f[0] = a.x;
    a.u = v.x & 0xFFFF0000u;  f[1] = a.x;
    a.u = v.y << 16;          f[2] = a.x;
    a.u = v.y & 0xFFFF0000u;  f[3] = a.x;
    a.u = v.z << 16;          f[4] = a.x;
    a.u = v.z & 0xFFFF0000u;  f[5] = a.x;
    a.u = v.w << 16;          f[6] = a.x;
    a.u = v.w & 0xFFFF0000u;  f[7] = a.x;
}

// ---------------- utility kernels ----------------

__global__ void zero_init_kernel(int* counts, float* pooled, int n, int np) {
    int t = blockIdx.x * blockDim.x + threadIdx.x;
    if (t < n) counts[t] = 0;
    if (t < np) pooled[t] = 0.0f;
}

__global__ void count_kernel(const int* __restrict__ ei, int* __restrict__ counts, int E) {
    int t = blockIdx.x * blockDim.x + threadIdx.x;
    if (t < E) atomicAdd(&counts[ei[E + t]], 1);
}

__global__ void scan_kernel(const int* __restrict__ counts, int* __restrict__ offsets,
                            int* __restrict__ cursor, int n) {
    __shared__ int part[1024];
    int t = threadIdx.x;
    int per = (n + 1023) / 1024;
    int base = t * per;
    int sum = 0;
    for (int j = 0; j < per; ++j) {
        int idx = base + j;
        if (idx < n) sum += counts[idx] + 1;
    }
    part[t] = sum;
    __syncthreads();
    for (int off = 1; off < 1024; off <<= 1) {
        int v = (t >= off) ? part[t - off] : 0;
        __syncthreads();
        part[t] += v;
        __syncthreads();
    }
    int run = (t == 0) ? 0 : part[t - 1];
    for (int j = 0; j < per; ++j) {
        int idx = base + j;
        if (idx < n) {
            int deg = counts[idx] + 1;
            offsets[idx] = run;
            cursor[idx] = run;
            run += deg;
        }
    }
    if (t == 1023) offsets[n] = part[1023];
}

__global__ void fill_kernel(const int* __restrict__ ei, int* __restrict__ cursor,
                            int* __restrict__ srcs, int E, int n) {
    int t = blockIdx.x * blockDim.x + threadIdx.x;
    if (t < E) {
        int s = ei[t];
        int d = ei[E + t];
        int slot = atomicAdd(&cursor[d], 1);
        srcs[slot] = s;
    } else if (t < E + n) {
        int i = t - E;
        int slot = atomicAdd(&cursor[i], 1);
        srcs[slot] = i;
    }
}

// ---------------- weight/input prep: fp32 -> bf16, concat ----------------
#define W_INP (IND * HCC)
#define W_CAT0 (IND * 2 * HCC)
#define W_CAT1 (HCC * 2 * HCC)
#define W_CAT2 (HCC * 2 * CC)
#define W_RES (HCC * CC)
#define XB_N (NN * IND)
#define PREP_TOTAL (W_INP + W_CAT0 + W_CAT1 + W_CAT2 + W_RES + XB_N + 2 * HCC + 2 * HCC + 2 * CC)

__global__ void prep_kernel(const float* __restrict__ x, const float* __restrict__ inp_w,
    const float* __restrict__ l0wl, const float* __restrict__ l0wr,
    const float* __restrict__ l1wl, const float* __restrict__ l1wr,
    const float* __restrict__ l2wl, const float* __restrict__ l2wr,
    const float* __restrict__ resw,
    const float* __restrict__ l0bl, const float* __restrict__ l0br,
    const float* __restrict__ l1bl, const float* __restrict__ l1br,
    const float* __restrict__ l2bl, const float* __restrict__ l2br,
    ushort_t* wInp, ushort_t* wCat0, ushort_t* wCat1, ushort_t* wCat2, ushort_t* wRes,
    ushort_t* xb, float* bc0, float* bc1, float* bc2)
{
    int i = blockIdx.x * blockDim.x + threadIdx.x;
    if (i >= PREP_TOTAL) return;
    if (i < W_INP) { wInp[i] = f2bf(inp_w[i]); return; }
    i -= W_INP;
    if (i < W_CAT0) {
        int row = i / (2 * HCC); int col = i - row * (2 * HCC);
        float v = col < HCC ? l0wl[row * HCC + col] : l0wr[row * HCC + col - HCC];
        wCat0[i] = f2bf(v); return;
    }
    i -= W_CAT0;
    if (i < W_CAT1) {
        int row = i / (2 * HCC); int col = i - row * (2 * HCC);
        float v = col < HCC ? l1wl[row * HCC + col] : l1wr[row * HCC + col - HCC];
        wCat1[i] = f2bf(v); return;
    }
    i -= W_CAT1;
    if (i < W_CAT2) {
        int row = i / (2 * CC); int col = i - row * (2 * CC);
        float v = col < CC ? l2wl[row * CC + col] : l2wr[row * CC + col - CC];
        wCat2[i] = f2bf(v); return;
    }
    i -= W_CAT2;
    if (i < W_RES) { wRes[i] = f2bf(resw[i]); return; }
    i -= W_RES;
    if (i < XB_N) { xb[i] = f2bf(x[i]); return; }
    i -= XB_N;
    if (i < 2 * HCC) { bc0[i] = i < HCC ? l0bl[i] : l0br[i - HCC]; return; }
    i -= 2 * HCC;
    if (i < 2 * HCC) { bc1[i] = i < HCC ? l1bl[i] : l1br[i - HCC]; return; }
    i -= 2 * HCC;
    if (i < 2 * CC) { bc2[i] = i < CC ? l2bl[i] : l2br[i - CC]; return; }
}

// ---------------- bf16 MFMA GEMM: C[M,N] = A[M,K]@B[K,N] + bias ----------------
__global__ __launch_bounds__(256) void gemm_mfma(
    const ushort_t* __restrict__ A, const ushort_t* __restrict__ B,
    const float* __restrict__ bias, float* __restrict__ Cf,
    ushort_t* __restrict__ Cb, int M, int N, int K)
{
    __shared__ ushort_t As[128 * 40];
    __shared__ ushort_t Bs[64 * 40];
    int t = threadIdx.x;
    int w = t >> 6, L = t & 63;
    int m0 = blockIdx.x * 128, n0 = blockIdx.y * 64;
    int q = L >> 4, r16 = L & 15;

    f32x4 acc[2][4];
#pragma unroll
    for (int a = 0; a < 2; ++a)
#pragma unroll
        for (int b = 0; b < 4; ++b) acc[a][b] = (f32x4){0.f, 0.f, 0.f, 0.f};

    int sa_r = t >> 2;
    int sa_k = (t & 3) * 8;
    int sb_k = t >> 3;
    int sb_n = (t & 7) * 8;
    int rot = (sb_n >> 3) & 7;

    for (int k0 = 0; k0 < K; k0 += 32) {
        __syncthreads();
#pragma unroll
        for (int rr0 = 0; rr0 < 2; ++rr0) {
            int rr = sa_r + rr0 * 64;
            int gm = m0 + rr;
            uint4 v = make_uint4(0u, 0u, 0u, 0u);
            if (gm < M) v = *(const uint4*)(A + (size_t)gm * K + k0 + sa_k);
            *(uint4*)(&As[rr * 40 + sa_k]) = v;
        }
        {
            uint4 v = *(const uint4*)(B + (size_t)(k0 + sb_k) * N + n0 + sb_n);
            ushort_t e[8];
            *(uint4*)e = v;
#pragma unroll
            for (int i = 0; i < 8; ++i) {
                int ii = (i + rot) & 7;
                Bs[(sb_n + ii) * 40 + sb_k] = e[ii];
            }
        }
        __syncthreads();
        bf16x8 a0 = *(const bf16x8*)&As[(w * 32 + r16) * 40 + q * 8];
        bf16x8 a1 = *(const bf16x8*)&As[(w * 32 + 16 + r16) * 40 + q * 8];
#pragma unroll
        for (int ct = 0; ct < 4; ++ct) {
            bf16x8 b = *(const bf16x8*)&Bs[(ct * 16 + r16) * 40 + q * 8];
            acc[0][ct] = __builtin_amdgcn_mfma_f32_16x16x32_bf16(a0, b, acc[0][ct], 0, 0, 0);
            acc[1][ct] = __builtin_amdgcn_mfma_f32_16x16x32_bf16(a1, b, acc[1][ct], 0, 0, 0);
        }
    }
#pragma unroll
    for (int rt = 0; rt < 2; ++rt) {
#pragma unroll
        for (int ct = 0; ct < 4; ++ct) {
            int col = n0 + ct * 16 + r16;
            float bv = bias ? bias[col] : 0.0f;
#pragma unroll
            for (int rr = 0; rr < 4; ++rr) {
                int row = m0 + w * 32 + rt * 16 + q * 4 + rr;
                if (row < M) {
                    float v = acc[rt][ct][rr] + bv;
                    if (Cf) Cf[(size_t)row * N + col] = v;
                    if (Cb) Cb[(size_t)row * N + col] = f2bf(v);
                }
            }
        }
    }
}

// ---------------- GATv2 H=6 (padded to 8): lane = (head, chan-group) ----------------
// cat: [n][768] bf16 = xl|xr. One wave per node. Per lane: 8 contiguous channels
// of one head -> 1 uint4 gather/edge, 3-shfl reduce, scalar (m,s) online softmax.
__global__ __launch_bounds__(256) void gat6_kernel(
    const ushort_t* __restrict__ cat, const float* __restrict__ att,
    const float* __restrict__ bias, const float* __restrict__ res,
    float* __restrict__ out, ushort_t* __restrict__ outB,
    const int* __restrict__ offsets, const int* __restrict__ srcs,
    float* __restrict__ ebuf, int n)
{
    int wid = (blockIdx.x * blockDim.x + threadIdx.x) >> 6;
    if (wid >= n) return;
    int lane = threadIdx.x & 63;
    int h = lane >> 3, c8 = lane & 7;
    int off = h * 64 + c8 * 8;          // 0..504 (h>=6 lanes are padding)
    bool hv = h < HH;
    int i = wid;
    int beg = offsets[i], end = offsets[i + 1];

    float xr8[8], att8[8];
    {
        uint4 v = *(const uint4*)(cat + (size_t)i * 768 + 384 + off);
        bf8cvt(v, xr8);
    }
#pragma unroll
    for (int j = 0; j < 8; ++j) att8[j] = hv ? att[off + j] : 0.0f;

    float m = -INFINITY, s = 0.0f;
    int sj = srcs[beg];
    for (int p = beg; p < end; ++p) {
        int sjn = (p + 1 < end) ? srcs[p + 1] : 0;
        uint4 v = *(const uint4*)(cat + (size_t)sj * 768 + off);
        float xl8[8];
        bf8cvt(v, xl8);
        float partial = 0.0f;
#pragma unroll
        for (int j = 0; j < 8; ++j) {
            float tv = xl8[j] + xr8[j];
            tv = fmaxf(tv, 0.2f * tv);           // leaky_relu(v,0.2) = max(v, 0.2v)
            partial = fmaf(tv, att8[j], partial);
        }
        partial += __shfl_xor(partial, 1, 64);
        partial += __shfl_xor(partial, 2, 64);
        partial += __shfl_xor(partial, 4, 64);
        float e = partial;
        float nm = fmaxf(m, e);
        s = s * __expf(m - nm) + __expf(e - nm);
        m = nm;
        if (c8 == 0 && hv) ebuf[(size_t)p * HH + h] = e;
        sj = sjn;
    }

    float inv = 1.0f / (s + 1e-16f);
    float acc8[8];
#pragma unroll
    for (int j = 0; j < 8; ++j) acc8[j] = 0.0f;
    int hm = hv ? h : (HH - 1);
    sj = srcs[beg];
    for (int p = beg; p < end; ++p) {
        int sjn = (p + 1 < end) ? srcs[p + 1] : 0;
        float e = ebuf[(size_t)p * HH + hm];
        float wgt = __expf(e - m) * inv;
        uint4 v = *(const uint4*)(cat + (size_t)sj * 768 + off);
        float xl8[8];
        bf8cvt(v, xl8);
#pragma unroll
        for (int j = 0; j < 8; ++j) acc8[j] = fmaf(xl8[j], wgt, acc8[j]);
        sj = sjn;
    }

    if (hv) {
        size_t ob = (size_t)i * HCC + off;
        float4 r0 = *(const float4*)(res + ob);
        float4 r1 = *(const float4*)(res + ob + 4);
        float rr[8] = {r0.x, r0.y, r0.z, r0.w, r1.x, r1.y, r1.z, r1.w};
#pragma unroll
        for (int j = 0; j < 8; ++j) {
            float v = acc8[j] + bias[off + j];
            v = v > 0.0f ? v : expm1f(v);
            acc8[j] = v + rr[j];
        }
        *(float4*)(out + ob) = make_float4(acc8[0], acc8[1], acc8[2], acc8[3]);
        *(float4*)(out + ob + 4) = make_float4(acc8[4], acc8[5], acc8[6], acc8[7]);
        if (outB) {
            ushort_t u[8];
#pragma unroll
            for (int j = 0; j < 8; ++j) u[j] = f2bf(acc8[j]);
            *(uint4*)(outB + ob) = *(uint4*)u;
        }
    }
}

// ---------------- GATv2 H=1: lane = (edge-group of 8, chan-group of 8) ----------------
// cat: [n][128] bf16 = xl|xr. 8 edges per wave-iteration.
__global__ __launch_bounds__(256) void gat1_kernel(
    const ushort_t* __restrict__ cat, const float* __restrict__ att,
    const float* __restrict__ bias, const float* __restrict__ res,
    float* __restrict__ out,
    const int* __restrict__ offsets, const int* __restrict__ srcs,
    float* __restrict__ ebuf, int n)
{
    int wid = (blockIdx.x * blockDim.x + threadIdx.x) >> 6;
    if (wid >= n) return;
    int lane = threadIdx.x & 63;
    int e8 = lane >> 3, c8 = lane & 7;
    int i = wid;
    int beg = offsets[i], end = offsets[i + 1];

    float xr8[8], att8[8];
    {
        uint4 v = *(const uint4*)(cat + (size_t)i * 128 + 64 + c8 * 8);
        bf8cvt(v, xr8);
    }
#pragma unroll
    for (int j = 0; j < 8; ++j) att8[j] = att[c8 * 8 + j];

    float m = -INFINITY, s = 0.0f;
    for (int p0 = beg; p0 < end; p0 += 8) {
        int p = p0 + e8;
        bool valid = p < end;
        int sj = valid ? srcs[p] : i;
        uint4 v = *(const uint4*)(cat + (size_t)sj * 128 + c8 * 8);
        float xl8[8];
        bf8cvt(v, xl8);
        float partial = 0.0f;
#pragma unroll
        for (int j = 0; j < 8; ++j) {
            float tv = xl8[j] + xr8[j];
            tv = fmaxf(tv, 0.2f * tv);
            partial = fmaf(tv, att8[j], partial);
        }
        partial += __shfl_xor(partial, 1, 64);
        partial += __shfl_xor(partial, 2, 64);
        partial += __shfl_xor(partial, 4, 64);
        float e = valid ? partial : -INFINITY;
        float bm = e;
        bm = fmaxf(bm, __shfl_xor(bm, 8, 64));
        bm = fmaxf(bm, __shfl_xor(bm, 16, 64));
        bm = fmaxf(bm, __shfl_xor(bm, 32, 64));
        float nm = fmaxf(m, bm);
        float pe = valid ? __expf(e - nm) : 0.0f;
        float se = pe;
        se += __shfl_xor(se, 8, 64);
        se += __shfl_xor(se, 16, 64);
        se += __shfl_xor(se, 32, 64);
        s = s * __expf(m - nm) + se;
        m = nm;
        if (valid && c8 == 0) ebuf[p] = e;
    }

    float inv = 1.0f / (s + 1e-16f);
    float acc8[8];
#pragma unroll
    for (int j = 0; j < 8; ++j) acc8[j] = 0.0f;
    for (int p0 = beg; p0 < end; p0 += 8) {
        int p = p0 + e8;
        bool valid = p < end;
        int sj = valid ? srcs[p] : i;
        float wgt = valid ? __expf(ebuf[p] - m) * inv : 0.0f;
        uint4 v = *(const uint4*)(cat + (size_t)sj * 128 + c8 * 8);
        float xl8[8];
        bf8cvt(v, xl8);
#pragma unroll
        for (int j = 0; j < 8; ++j) acc8[j] = fmaf(xl8[j], wgt, acc8[j]);
    }
#pragma unroll
    for (int j = 0; j < 8; ++j) {
        acc8[j] += __shfl_xor(acc8[j], 8, 64);
        acc8[j] += __shfl_xor(acc8[j], 16, 64);
        acc8[j] += __shfl_xor(acc8[j], 32, 64);
    }
    if (e8 == 0) {
        size_t ob = (size_t)i * CC + c8 * 8;
        float4 r0 = *(const float4*)(res + ob);
        float4 r1 = *(const float4*)(res + ob + 4);
        float rr[8] = {r0.x, r0.y, r0.z, r0.w, r1.x, r1.y, r1.z, r1.w};
#pragma unroll
        for (int j = 0; j < 8; ++j) {
            float v = acc8[j] + bias[c8 * 8 + j];
            v = v > 0.0f ? v : expm1f(v);
            acc8[j] = v + rr[j];
        }
        *(float4*)(out + ob) = make_float4(acc8[0], acc8[1], acc8[2], acc8[3]);
        *(float4*)(out + ob + 4) = make_float4(acc8[4], acc8[5], acc8[6], acc8[7]);
    }
}

// ---------------- pooling (batch is sorted) ----------------
__global__ void pool_kernel(const float* __restrict__ h, const int* __restrict__ batch,
                            float* __restrict__ pooled, int n) {
    const int CHUNK = 128;
    int start = blockIdx.x * CHUNK;
    int lane = threadIdx.x;  // 64
    if (start >= n) return;
    int end = start + CHUNK;
    if (end > n) end = n;
    float acc = 0.0f;
    int cur = batch[start];
    for (int i = start; i < end; ++i) {
        int g = batch[i];
        if (g != cur) {
            atomicAdd(&pooled[cur * 64 + lane], acc);
            acc = 0.0f;
            cur = g;
        }
        acc += h[(size_t)i * 64 + lane];
    }
    atomicAdd(&pooled[cur * 64 + lane], acc);
}

// ---------------- dense head ----------------
__global__ void head_kernel(const float* __restrict__ pooled,
                            const float* __restrict__ d1w, const float* __restrict__ d1b,
                            const float* __restrict__ bng, const float* __restrict__ bnb,
                            const float* __restrict__ bnm, const float* __restrict__ bnv,
                            const float* __restrict__ d2w, const float* __restrict__ d2b,
                            float* __restrict__ zout) {
    __shared__ float z1[64 * 64];
    int t = threadIdx.x;  // 256
    for (int idx = t; idx < 64 * 64; idx += 256) {
        int r = idx >> 6, c = idx & 63;
        float acc = d1b[c];
        for (int k = 0; k < 64; ++k) acc += pooled[r * 64 + k] * d1w[k * 64 + c];
        acc = (acc - bnm[c]) / sqrtf(bnv[c] + 1e-5f) * bng[c] + bnb[c];
        z1[idx] = acc > 0.0f ? acc : 0.0f;
    }
    __syncthreads();
    for (int idx = t; idx < 64 * NCC; idx += 256) {
        int r = idx >> 4, c = idx & 15;
        float acc = d2b[c];
        for (int k = 0; k < 64; ++k) acc += z1[r * 64 + k] * d2w[k * NCC + c];
        zout[idx] = acc;
    }
}

// ---------------- launcher ----------------

extern "C" void kernel_launch(void* const* d_in, const int* in_sizes, int n_in,
                              void* d_out, int out_size, void* d_ws, size_t ws_size,
                              hipStream_t stream) {
    const int N = NN, E = EE, C = CC, HC = HCC, NG = NGG;
    const int EN = E + N;

    const float* x     = (const float*)d_in[0];
    const int*   ei    = (const int*)d_in[1];
    const int*   batch = (const int*)d_in[2];
    const float* inp_w = (const float*)d_in[3];
    const float* inp_b = (const float*)d_in[4];
    const float* l0_wl = (const float*)d_in[5];
    const float* l0_bl = (const float*)d_in[6];
    const float* l0_wr = (const float*)d_in[7];
    const float* l0_br = (const float*)d_in[8];
    const float* l0_att = (const float*)d_in[9];
    const float* l0_bias = (const float*)d_in[10];
    const float* l1_wl = (const float*)d_in[11];
    const float* l1_bl = (const float*)d_in[12];
    const float* l1_wr = (const float*)d_in[13];
    const float* l1_br = (const float*)d_in[14];
    const float* l1_att = (const float*)d_in[15];
    const float* l1_bias = (const float*)d_in[16];
    const float* l2_wl = (const float*)d_in[17];
    const float* l2_bl = (const float*)d_in[18];
    const float* l2_wr = (const float*)d_in[19];
    const float* l2_br = (const float*)d_in[20];
    const float* l2_att = (const float*)d_in[21];
    const float* l2_bias = (const float*)d_in[22];
    const float* res_w = (const float*)d_in[23];
    const float* d1_w = (const float*)d_in[24];
    const float* d1_b = (const float*)d_in[25];
    const float* bn_g = (const float*)d_in[26];
    const float* bn_b = (const float*)d_in[27];
    const float* bn_m = (const float*)d_in[28];
    const float* bn_v = (const float*)d_in[29];
    const float* d2_w = (const float*)d_in[30];
    const float* d2_b = (const float*)d_in[31];

    float* out = (float*)d_out;

    char* ws = (char*)d_ws;
    size_t off = 0;
    auto alloc = [&](size_t bytes) -> void* {
        void* p = ws + off;
        off += (bytes + 255) & ~(size_t)255;
        return p;
    };
    float*    bufH    = (float*)alloc((size_t)N * HC * 4);
    ushort_t* bufH_b  = (ushort_t*)alloc((size_t)N * HC * 2);
    ushort_t* cat01_b = (ushort_t*)alloc((size_t)N * 768 * 2 + 2048);  // pad: gat6 h>=6 lanes overread
    float*    bufXres = (float*)alloc((size_t)N * HC * 4);
    ushort_t* cat2_b  = (ushort_t*)alloc((size_t)N * 128 * 2);
    float*    bufRes  = (float*)alloc((size_t)N * C * 4);
    ushort_t* xb      = (ushort_t*)alloc((size_t)N * IND * 2);
    ushort_t* wInp    = (ushort_t*)alloc((size_t)W_INP * 2);
    ushort_t* wCat0   = (ushort_t*)alloc((size_t)W_CAT0 * 2);
    ushort_t* wCat1   = (ushort_t*)alloc((size_t)W_CAT1 * 2);
    ushort_t* wCat2   = (ushort_t*)alloc((size_t)W_CAT2 * 2);
    ushort_t* wRes    = (ushort_t*)alloc((size_t)W_RES * 2);
    float*    bc0     = (float*)alloc((size_t)2 * HC * 4);
    float*    bc1     = (float*)alloc((size_t)2 * HC * 4);
    float*    bc2     = (float*)alloc((size_t)2 * C * 4);
    float*    ebuf    = (float*)alloc((size_t)EN * HH * 4);
    int*      counts  = (int*)alloc((size_t)N * 4);
    int*      cursor  = (int*)alloc((size_t)N * 4);
    int*      offsets = (int*)alloc((size_t)(N + 1) * 4);
    int*      srcs    = (int*)alloc((size_t)EN * 4);
    float*    pooled  = (float*)alloc((size_t)NG * C * 4);

    int zi_n = N > NG * C ? N : NG * C;
    zero_init_kernel<<<(zi_n + 255) / 256, 256, 0, stream>>>(counts, pooled, N, NG * C);
    count_kernel<<<(E + 255) / 256, 256, 0, stream>>>(ei, counts, E);
    scan_kernel<<<1, 1024, 0, stream>>>(counts, offsets, cursor, N);
    fill_kernel<<<(EN + 255) / 256, 256, 0, stream>>>(ei, cursor, srcs, E, N);
    prep_kernel<<<(PREP_TOTAL + 255) / 256, 256, 0, stream>>>(
        x, inp_w, l0_wl, l0_wr, l1_wl, l1_wr, l2_wl, l2_wr, res_w,
        l0_bl, l0_br, l1_bl, l1_br, l2_bl, l2_br,
        wInp, wCat0, wCat1, wCat2, wRes, xb, bc0, bc1, bc2);

    dim3 blk(256);
    int mtiles = (N + 127) / 128;
    int gatBlocks = (N * 64 + 255) / 256;

    // x_res = x @ inp_w + inp_b  (fp32 out)
    gemm_mfma<<<dim3(mtiles, HC / 64), blk, 0, stream>>>(xb, wInp, inp_b, bufXres, nullptr, N, HC, IND);
    // layer 0 xl|xr (bf16 out)
    gemm_mfma<<<dim3(mtiles, 768 / 64), blk, 0, stream>>>(xb, wCat0, bc0, nullptr, cat01_b, N, 768, IND);
    gat6_kernel<<<gatBlocks, blk, 0, stream>>>(cat01_b, l0_att, l0_bias,
                                               bufXres, bufH, bufH_b, offsets, srcs, ebuf, N);
    // layer 1
    gemm_mfma<<<dim3(mtiles, 768 / 64), blk, 0, stream>>>(bufH_b, wCat1, bc1, nullptr, cat01_b, N, 768, HC);
    gat6_kernel<<<gatBlocks, blk, 0, stream>>>(cat01_b, l1_att, l1_bias,
                                               bufH, bufH, bufH_b, offsets, srcs, ebuf, N);
    // layer 2 (H=1) + residual projection
    gemm_mfma<<<dim3(mtiles, 128 / 64), blk, 0, stream>>>(bufH_b, wCat2, bc2, nullptr, cat2_b, N, 128, HC);
    gemm_mfma<<<dim3(mtiles, 64 / 64), blk, 0, stream>>>(bufH_b, wRes, nullptr, bufRes, nullptr, N, C, HC);
    gat1_kernel<<<gatBlocks, blk, 0, stream>>>(cat2_b, l2_att, l2_bias,
                                               bufRes, out, offsets, srcs, ebuf, N);
    // pooling + head
    pool_kernel<<<(N + 127) / 128, 64, 0, stream>>>(out, batch, pooled, N);
    head_kernel<<<1, 256, 0, stream>>>(pooled, d1_w, d1_b, bn_g, bn_b, bn_m, bn_v,
                                       d2_w, d2_b, out + (size_t)N * C);
}

// Round 4
// 576.712 us; speedup vs baseline: 1.9095x; 1.1349x over previous
//
#include <hip/hip_runtime.h>
#include <hip/hip_bf16.h>
#include <math.h>

#define NN 20000
#define EE 320000
#define IND 128
#define HH 6
#define CC 64
#define HCC 384
#define NCC 16
#define NGG 64

typedef __bf16 bf16x8 __attribute__((ext_vector_type(8)));
typedef float f32x4 __attribute__((ext_vector_type(4)));
typedef unsigned short ushort_t;
typedef unsigned int uint_t;

__device__ inline ushort_t f2bf(float f) {
    union { float f; uint_t u; } x; x.f = f;
    uint_t r = (x.u + 0x7FFF + ((x.u >> 16) & 1)) >> 16;
    return (ushort_t)r;
}
__device__ inline float bf2f(ushort_t h) {
    union { uint_t u; float f; } x; x.u = ((uint_t)h) << 16; return x.f;
}
// 8 packed bf16 (uint4) -> 8 floats
__device__ inline void bf8cvt(uint4 v, float* f) {
    union { uint_t u; float x; } a;
    a.u = v.x << 16;          f[0] = a.x;
    a.u = v.x & 0xFFFF0000u;  f[1] = a.x;
    a.u = v.y << 16;          f[2] = a.x;
    a.u = v.y & 0xFFFF0000u;  f[3] = a.x;
    a.u = v.z << 16;          f[4] = a.x;
    a.u = v.z & 0xFFFF0000u;  f[5] = a.x;
    a.u = v.w << 16;          f[6] = a.x;
    a.u = v.w & 0xFFFF0000u;  f[7] = a.x;
}

// ---------------- utility kernels ----------------

__global__ void zero_init_kernel(int* counts, float* pooled, int n, int np) {
    int t = blockIdx.x * blockDim.x + threadIdx.x;
    if (t < n) counts[t] = 0;
    if (t < np) pooled[t] = 0.0f;
}

__global__ void count_kernel(const int* __restrict__ ei, int* __restrict__ counts, int E) {
    int t = blockIdx.x * blockDim.x + threadIdx.x;
    if (t < E) atomicAdd(&counts[ei[E + t]], 1);
}

__global__ void scan_kernel(const int* __restrict__ counts, int* __restrict__ offsets,
                            int* __restrict__ cursor, int n) {
    __shared__ int part[1024];
    int t = threadIdx.x;
    int per = (n + 1023) / 1024;
    int base = t * per;
    int sum = 0;
    for (int j = 0; j < per; ++j) {
        int idx = base + j;
        if (idx < n) sum += counts[idx] + 1;
    }
    part[t] = sum;
    __syncthreads();
    for (int off = 1; off < 1024; off <<= 1) {
        int v = (t >= off) ? part[t - off] : 0;
        __syncthreads();
        part[t] += v;
        __syncthreads();
    }
    int run = (t == 0) ? 0 : part[t - 1];
    for (int j = 0; j < per; ++j) {
        int idx = base + j;
        if (idx < n) {
            int deg = counts[idx] + 1;
            offsets[idx] = run;
            cursor[idx] = run;
            run += deg;
        }
    }
    if (t == 1023) offsets[n] = part[1023];
}

__global__ void fill_kernel(const int* __restrict__ ei, int* __restrict__ cursor,
                            int* __restrict__ srcs, int E, int n) {
    int t = blockIdx.x * blockDim.x + threadIdx.x;
    if (t < E) {
        int s = ei[t];
        int d = ei[E + t];
        int slot = atomicAdd(&cursor[d], 1);
        srcs[slot] = s;
    } else if (t < E + n) {
        int i = t - E;
        int slot = atomicAdd(&cursor[i], 1);
        srcs[slot] = i;
    }
}

// ---------------- weight/input prep: fp32 -> bf16, concat ----------------
#define W_INP (IND * HCC)
#define W_CAT0 (IND * 2 * HCC)
#define W_CAT1 (HCC * 2 * HCC)
#define W_CAT2 (HCC * 2 * CC)
#define W_RES (HCC * CC)
#define XB_N (NN * IND)
#define PREP_TOTAL (W_INP + W_CAT0 + W_CAT1 + W_CAT2 + W_RES + XB_N + 2 * HCC + 2 * HCC + 2 * CC)

__global__ void prep_kernel(const float* __restrict__ x, const float* __restrict__ inp_w,
    const float* __restrict__ l0wl, const float* __restrict__ l0wr,
    const float* __restrict__ l1wl, const float* __restrict__ l1wr,
    const float* __restrict__ l2wl, const float* __restrict__ l2wr,
    const float* __restrict__ resw,
    const float* __restrict__ l0bl, const float* __restrict__ l0br,
    const float* __restrict__ l1bl, const float* __restrict__ l1br,
    const float* __restrict__ l2bl, const float* __restrict__ l2br,
    ushort_t* wInp, ushort_t* wCat0, ushort_t* wCat1, ushort_t* wCat2, ushort_t* wRes,
    ushort_t* xb, float* bc0, float* bc1, float* bc2)
{
    int i = blockIdx.x * blockDim.x + threadIdx.x;
    if (i >= PREP_TOTAL) return;
    if (i < W_INP) { wInp[i] = f2bf(inp_w[i]); return; }
    i -= W_INP;
    if (i < W_CAT0) {
        int row = i / (2 * HCC); int col = i - row * (2 * HCC);
        float v = col < HCC ? l0wl[row * HCC + col] : l0wr[row * HCC + col - HCC];
        wCat0[i] = f2bf(v); return;
    }
    i -= W_CAT0;
    if (i < W_CAT1) {
        int row = i / (2 * HCC); int col = i - row * (2 * HCC);
        float v = col < HCC ? l1wl[row * HCC + col] : l1wr[row * HCC + col - HCC];
        wCat1[i] = f2bf(v); return;
    }
    i -= W_CAT1;
    if (i < W_CAT2) {
        int row = i / (2 * CC); int col = i - row * (2 * CC);
        float v = col < CC ? l2wl[row * CC + col] : l2wr[row * CC + col - CC];
        wCat2[i] = f2bf(v); return;
    }
    i -= W_CAT2;
    if (i < W_RES) { wRes[i] = f2bf(resw[i]); return; }
    i -= W_RES;
    if (i < XB_N) { xb[i] = f2bf(x[i]); return; }
    i -= XB_N;
    if (i < 2 * HCC) { bc0[i] = i < HCC ? l0bl[i] : l0br[i - HCC]; return; }
    i -= 2 * HCC;
    if (i < 2 * HCC) { bc1[i] = i < HCC ? l1bl[i] : l1br[i - HCC]; return; }
    i -= 2 * HCC;
    if (i < 2 * CC) { bc2[i] = i < CC ? l2bl[i] : l2br[i - CC]; return; }
}

// ---------------- bf16 MFMA GEMM: C[M,N] = A[M,K]@B[K,N] + bias ----------------
__global__ __launch_bounds__(256) void gemm_mfma(
    const ushort_t* __restrict__ A, const ushort_t* __restrict__ B,
    const float* __restrict__ bias, float* __restrict__ Cf,
    ushort_t* __restrict__ Cb, int M, int N, int K)
{
    __shared__ ushort_t As[128 * 40];
    __shared__ ushort_t Bs[64 * 40];
    int t = threadIdx.x;
    int w = t >> 6, L = t & 63;
    int m0 = blockIdx.x * 128, n0 = blockIdx.y * 64;
    int q = L >> 4, r16 = L & 15;

    f32x4 acc[2][4];
#pragma unroll
    for (int a = 0; a < 2; ++a)
#pragma unroll
        for (int b = 0; b < 4; ++b) acc[a][b] = (f32x4){0.f, 0.f, 0.f, 0.f};

    int sa_r = t >> 2;
    int sa_k = (t & 3) * 8;
    int sb_k = t >> 3;
    int sb_n = (t & 7) * 8;
    int rot = (sb_n >> 3) & 7;

    for (int k0 = 0; k0 < K; k0 += 32) {
        __syncthreads();
#pragma unroll
        for (int rr0 = 0; rr0 < 2; ++rr0) {
            int rr = sa_r + rr0 * 64;
            int gm = m0 + rr;
            uint4 v = make_uint4(0u, 0u, 0u, 0u);
            if (gm < M) v = *(const uint4*)(A + (size_t)gm * K + k0 + sa_k);
            *(uint4*)(&As[rr * 40 + sa_k]) = v;
        }
        {
            uint4 v = *(const uint4*)(B + (size_t)(k0 + sb_k) * N + n0 + sb_n);
            ushort_t e[8];
            *(uint4*)e = v;
#pragma unroll
            for (int i = 0; i < 8; ++i) {
                int ii = (i + rot) & 7;
                Bs[(sb_n + ii) * 40 + sb_k] = e[ii];
            }
        }
        __syncthreads();
        bf16x8 a0 = *(const bf16x8*)&As[(w * 32 + r16) * 40 + q * 8];
        bf16x8 a1 = *(const bf16x8*)&As[(w * 32 + 16 + r16) * 40 + q * 8];
#pragma unroll
        for (int ct = 0; ct < 4; ++ct) {
            bf16x8 b = *(const bf16x8*)&Bs[(ct * 16 + r16) * 40 + q * 8];
            acc[0][ct] = __builtin_amdgcn_mfma_f32_16x16x32_bf16(a0, b, acc[0][ct], 0, 0, 0);
            acc[1][ct] = __builtin_amdgcn_mfma_f32_16x16x32_bf16(a1, b, acc[1][ct], 0, 0, 0);
        }
    }
#pragma unroll
    for (int rt = 0; rt < 2; ++rt) {
#pragma unroll
        for (int ct = 0; ct < 4; ++ct) {
            int col = n0 + ct * 16 + r16;
            float bv = bias ? bias[col] : 0.0f;
#pragma unroll
            for (int rr = 0; rr < 4; ++rr) {
                int row = m0 + w * 32 + rt * 16 + q * 4 + rr;
                if (row < M) {
                    float v = acc[rt][ct][rr] + bv;
                    if (Cf) Cf[(size_t)row * N + col] = v;
                    if (Cb) Cb[(size_t)row * N + col] = f2bf(v);
                }
            }
        }
    }
}

// ---------------- GATv2 H=6: single-pass flash-style online softmax ----------------
// lane = (head h = lane>>3 [0..7, 6-7 masked], chan-group c8 = lane&7).
// Per edge: one predicated uint4 gather (768B/wave), 3-shfl dot reduce,
// online (m,s) + accumulator rescale. No second pass, no ebuf.
__global__ __launch_bounds__(256) void gat6_kernel(
    const ushort_t* __restrict__ cat, const float* __restrict__ att,
    const float* __restrict__ bias, const float* __restrict__ res,
    float* __restrict__ out, ushort_t* __restrict__ outB,
    const int* __restrict__ offsets, const int* __restrict__ srcs, int n)
{
    int wid = (blockIdx.x * blockDim.x + threadIdx.x) >> 6;
    if (wid >= n) return;
    int lane = threadIdx.x & 63;
    int h = lane >> 3, c8 = lane & 7;
    int off = h * 64 + c8 * 8;
    bool hv = h < HH;
    int i = wid;
    int beg = offsets[i], end = offsets[i + 1];

    float xr8[8], att8[8];
    {
        uint4 v = make_uint4(0u, 0u, 0u, 0u);
        if (hv) v = *(const uint4*)(cat + (size_t)i * 768 + 384 + off);
        bf8cvt(v, xr8);
    }
#pragma unroll
    for (int j = 0; j < 8; ++j) att8[j] = hv ? att[off + j] : 0.0f;

    float m = -INFINITY, s = 0.0f;
    float acc8[8];
#pragma unroll
    for (int j = 0; j < 8; ++j) acc8[j] = 0.0f;

    int sj = srcs[beg];
    for (int p = beg; p < end; ++p) {
        int sjn = (p + 1 < end) ? srcs[p + 1] : 0;
        uint4 v = make_uint4(0u, 0u, 0u, 0u);
        if (hv) v = *(const uint4*)(cat + (size_t)sj * 768 + off);
        float xl8[8];
        bf8cvt(v, xl8);
        float partial = 0.0f;
#pragma unroll
        for (int j = 0; j < 8; ++j) {
            float tv = xl8[j] + xr8[j];
            tv = fmaxf(tv, 0.2f * tv);           // leaky_relu 0.2
            partial = fmaf(tv, att8[j], partial);
        }
        partial += __shfl_xor(partial, 1, 64);
        partial += __shfl_xor(partial, 2, 64);
        partial += __shfl_xor(partial, 4, 64);
        float e = partial;
        float nm = fmaxf(m, e);
        float scale = __expf(m - nm);
        float pe = __expf(e - nm);
        s = s * scale + pe;
#pragma unroll
        for (int j = 0; j < 8; ++j) acc8[j] = fmaf(acc8[j], scale, pe * xl8[j]);
        m = nm;
        sj = sjn;
    }

    if (hv) {
        float inv = 1.0f / (s + 1e-16f);
        size_t ob = (size_t)i * HCC + off;
        float4 r0 = *(const float4*)(res + ob);
        float4 r1 = *(const float4*)(res + ob + 4);
        float rr[8] = {r0.x, r0.y, r0.z, r0.w, r1.x, r1.y, r1.z, r1.w};
#pragma unroll
        for (int j = 0; j < 8; ++j) {
            float v = acc8[j] * inv + bias[off + j];
            v = v > 0.0f ? v : expm1f(v);
            acc8[j] = v + rr[j];
        }
        *(float4*)(out + ob) = make_float4(acc8[0], acc8[1], acc8[2], acc8[3]);
        *(float4*)(out + ob + 4) = make_float4(acc8[4], acc8[5], acc8[6], acc8[7]);
        if (outB) {
            ushort_t u[8];
#pragma unroll
            for (int j = 0; j < 8; ++j) u[j] = f2bf(acc8[j]);
            *(uint4*)(outB + ob) = *(uint4*)u;
        }
    }
}

// ---------------- GATv2 H=1: single-pass, 8 edges per wave-iteration ----------------
__global__ __launch_bounds__(256) void gat1_kernel(
    const ushort_t* __restrict__ cat, const float* __restrict__ att,
    const float* __restrict__ bias, const float* __restrict__ res,
    float* __restrict__ out,
    const int* __restrict__ offsets, const int* __restrict__ srcs, int n)
{
    int wid = (blockIdx.x * blockDim.x + threadIdx.x) >> 6;
    if (wid >= n) return;
    int lane = threadIdx.x & 63;
    int e8 = lane >> 3, c8 = lane & 7;
    int i = wid;
    int beg = offsets[i], end = offsets[i + 1];

    float xr8[8], att8[8];
    {
        uint4 v = *(const uint4*)(cat + (size_t)i * 128 + 64 + c8 * 8);
        bf8cvt(v, xr8);
    }
#pragma unroll
    for (int j = 0; j < 8; ++j) att8[j] = att[c8 * 8 + j];

    float m = -INFINITY, s = 0.0f;
    float acc8[8];
#pragma unroll
    for (int j = 0; j < 8; ++j) acc8[j] = 0.0f;

    for (int p0 = beg; p0 < end; p0 += 8) {
        int p = p0 + e8;
        bool valid = p < end;
        int sj = valid ? srcs[p] : i;
        uint4 v = *(const uint4*)(cat + (size_t)sj * 128 + c8 * 8);
        float xl8[8];
        bf8cvt(v, xl8);
        float partial = 0.0f;
#pragma unroll
        for (int j = 0; j < 8; ++j) {
            float tv = xl8[j] + xr8[j];
            tv = fmaxf(tv, 0.2f * tv);
            partial = fmaf(tv, att8[j], partial);
        }
        partial += __shfl_xor(partial, 1, 64);
        partial += __shfl_xor(partial, 2, 64);
        partial += __shfl_xor(partial, 4, 64);
        float e = valid ? partial : -INFINITY;
        float bm = e;
        bm = fmaxf(bm, __shfl_xor(bm, 8, 64));
        bm = fmaxf(bm, __shfl_xor(bm, 16, 64));
        bm = fmaxf(bm, __shfl_xor(bm, 32, 64));
        float nm = fmaxf(m, bm);
        float scale = __expf(m - nm);
        float pe = valid ? __expf(e - nm) : 0.0f;
        float se = pe;
        se += __shfl_xor(se, 8, 64);
        se += __shfl_xor(se, 16, 64);
        se += __shfl_xor(se, 32, 64);
        s = s * scale + se;
#pragma unroll
        for (int j = 0; j < 8; ++j) acc8[j] = fmaf(acc8[j], scale, pe * xl8[j]);
        m = nm;
    }

#pragma unroll
    for (int j = 0; j < 8; ++j) {
        acc8[j] += __shfl_xor(acc8[j], 8, 64);
        acc8[j] += __shfl_xor(acc8[j], 16, 64);
        acc8[j] += __shfl_xor(acc8[j], 32, 64);
    }
    if (e8 == 0) {
        float inv = 1.0f / (s + 1e-16f);
        size_t ob = (size_t)i * CC + c8 * 8;
        float4 r0 = *(const float4*)(res + ob);
        float4 r1 = *(const float4*)(res + ob + 4);
        float rr[8] = {r0.x, r0.y, r0.z, r0.w, r1.x, r1.y, r1.z, r1.w};
#pragma unroll
        for (int j = 0; j < 8; ++j) {
            float v = acc8[j] * inv + bias[c8 * 8 + j];
            v = v > 0.0f ? v : expm1f(v);
            acc8[j] = v + rr[j];
        }
        *(float4*)(out + ob) = make_float4(acc8[0], acc8[1], acc8[2], acc8[3]);
        *(float4*)(out + ob + 4) = make_float4(acc8[4], acc8[5], acc8[6], acc8[7]);
    }
}

// ---------------- pooling (batch is sorted) ----------------
__global__ void pool_kernel(const float* __restrict__ h, const int* __restrict__ batch,
                            float* __restrict__ pooled, int n) {
    const int CHUNK = 128;
    int start = blockIdx.x * CHUNK;
    int lane = threadIdx.x;  // 64
    if (start >= n) return;
    int end = start + CHUNK;
    if (end > n) end = n;
    float acc = 0.0f;
    int cur = batch[start];
    for (int i = start; i < end; ++i) {
        int g = batch[i];
        if (g != cur) {
            atomicAdd(&pooled[cur * 64 + lane], acc);
            acc = 0.0f;
            cur = g;
        }
        acc += h[(size_t)i * 64 + lane];
    }
    atomicAdd(&pooled[cur * 64 + lane], acc);
}

// ---------------- dense head ----------------
__global__ void head_kernel(const float* __restrict__ pooled,
                            const float* __restrict__ d1w, const float* __restrict__ d1b,
                            const float* __restrict__ bng, const float* __restrict__ bnb,
                            const float* __restrict__ bnm, const float* __restrict__ bnv,
                            const float* __restrict__ d2w, const float* __restrict__ d2b,
                            float* __restrict__ zout) {
    __shared__ float z1[64 * 64];
    int t = threadIdx.x;  // 256
    for (int idx = t; idx < 64 * 64; idx += 256) {
        int r = idx >> 6, c = idx & 63;
        float acc = d1b[c];
        for (int k = 0; k < 64; ++k) acc += pooled[r * 64 + k] * d1w[k * 64 + c];
        acc = (acc - bnm[c]) / sqrtf(bnv[c] + 1e-5f) * bng[c] + bnb[c];
        z1[idx] = acc > 0.0f ? acc : 0.0f;
    }
    __syncthreads();
    for (int idx = t; idx < 64 * NCC; idx += 256) {
        int r = idx >> 4, c = idx & 15;
        float acc = d2b[c];
        for (int k = 0; k < 64; ++k) acc += z1[r * 64 + k] * d2w[k * NCC + c];
        zout[idx] = acc;
    }
}

// ---------------- launcher ----------------

extern "C" void kernel_launch(void* const* d_in, const int* in_sizes, int n_in,
                              void* d_out, int out_size, void* d_ws, size_t ws_size,
                              hipStream_t stream) {
    const int N = NN, E = EE, C = CC, HC = HCC, NG = NGG;
    const int EN = E + N;

    const float* x     = (const float*)d_in[0];
    const int*   ei    = (const int*)d_in[1];
    const int*   batch = (const int*)d_in[2];
    const float* inp_w = (const float*)d_in[3];
    const float* inp_b = (const float*)d_in[4];
    const float* l0_wl = (const float*)d_in[5];
    const float* l0_bl = (const float*)d_in[6];
    const float* l0_wr = (const float*)d_in[7];
    const float* l0_br = (const float*)d_in[8];
    const float* l0_att = (const float*)d_in[9];
    const float* l0_bias = (const float*)d_in[10];
    const float* l1_wl = (const float*)d_in[11];
    const float* l1_bl = (const float*)d_in[12];
    const float* l1_wr = (const float*)d_in[13];
    const float* l1_br = (const float*)d_in[14];
    const float* l1_att = (const float*)d_in[15];
    const float* l1_bias = (const float*)d_in[16];
    const float* l2_wl = (const float*)d_in[17];
    const float* l2_bl = (const float*)d_in[18];
    const float* l2_wr = (const float*)d_in[19];
    const float* l2_br = (const float*)d_in[20];
    const float* l2_att = (const float*)d_in[21];
    const float* l2_bias = (const float*)d_in[22];
    const float* res_w = (const float*)d_in[23];
    const float* d1_w = (const float*)d_in[24];
    const float* d1_b = (const float*)d_in[25];
    const float* bn_g = (const float*)d_in[26];
    const float* bn_b = (const float*)d_in[27];
    const float* bn_m = (const float*)d_in[28];
    const float* bn_v = (const float*)d_in[29];
    const float* d2_w = (const float*)d_in[30];
    const float* d2_b = (const float*)d_in[31];

    float* out = (float*)d_out;

    char* ws = (char*)d_ws;
    size_t off = 0;
    auto alloc = [&](size_t bytes) -> void* {
        void* p = ws + off;
        off += (bytes + 255) & ~(size_t)255;
        return p;
    };
    float*    bufH    = (float*)alloc((size_t)N * HC * 4);
    ushort_t* bufH_b  = (ushort_t*)alloc((size_t)N * HC * 2);
    ushort_t* cat01_b = (ushort_t*)alloc((size_t)N * 768 * 2 + 2048);
    float*    bufXres = (float*)alloc((size_t)N * HC * 4);
    ushort_t* cat2_b  = (ushort_t*)alloc((size_t)N * 128 * 2);
    float*    bufRes  = (float*)alloc((size_t)N * C * 4);
    ushort_t* xb      = (ushort_t*)alloc((size_t)N * IND * 2);
    ushort_t* wInp    = (ushort_t*)alloc((size_t)W_INP * 2);
    ushort_t* wCat0   = (ushort_t*)alloc((size_t)W_CAT0 * 2);
    ushort_t* wCat1   = (ushort_t*)alloc((size_t)W_CAT1 * 2);
    ushort_t* wCat2   = (ushort_t*)alloc((size_t)W_CAT2 * 2);
    ushort_t* wRes    = (ushort_t*)alloc((size_t)W_RES * 2);
    float*    bc0     = (float*)alloc((size_t)2 * HC * 4);
    float*    bc1     = (float*)alloc((size_t)2 * HC * 4);
    float*    bc2     = (float*)alloc((size_t)2 * C * 4);
    int*      counts  = (int*)alloc((size_t)N * 4);
    int*      cursor  = (int*)alloc((size_t)N * 4);
    int*      offsets = (int*)alloc((size_t)(N + 1) * 4);
    int*      srcs    = (int*)alloc((size_t)EN * 4);
    float*    pooled  = (float*)alloc((size_t)NG * C * 4);

    int zi_n = N > NG * C ? N : NG * C;
    zero_init_kernel<<<(zi_n + 255) / 256, 256, 0, stream>>>(counts, pooled, N, NG * C);
    count_kernel<<<(E + 255) / 256, 256, 0, stream>>>(ei, counts, E);
    scan_kernel<<<1, 1024, 0, stream>>>(counts, offsets, cursor, N);
    fill_kernel<<<(EN + 255) / 256, 256, 0, stream>>>(ei, cursor, srcs, E, N);
    prep_kernel<<<(PREP_TOTAL + 255) / 256, 256, 0, stream>>>(
        x, inp_w, l0_wl, l0_wr, l1_wl, l1_wr, l2_wl, l2_wr, res_w,
        l0_bl, l0_br, l1_bl, l1_br, l2_bl, l2_br,
        wInp, wCat0, wCat1, wCat2, wRes, xb, bc0, bc1, bc2);

    dim3 blk(256);
    int mtiles = (N + 127) / 128;
    int gatBlocks = (N * 64 + 255) / 256;

    // x_res = x @ inp_w + inp_b  (fp32 out)
    gemm_mfma<<<dim3(mtiles, HC / 64), blk, 0, stream>>>(xb, wInp, inp_b, bufXres, nullptr, N, HC, IND);
    // layer 0 xl|xr (bf16 out)
    gemm_mfma<<<dim3(mtiles, 768 / 64), blk, 0, stream>>>(xb, wCat0, bc0, nullptr, cat01_b, N, 768, IND);
    gat6_kernel<<<gatBlocks, blk, 0, stream>>>(cat01_b, l0_att, l0_bias,
                                               bufXres, bufH, bufH_b, offsets, srcs, N);
    // layer 1
    gemm_mfma<<<dim3(mtiles, 768 / 64), blk, 0, stream>>>(bufH_b, wCat1, bc1, nullptr, cat01_b, N, 768, HC);
    gat6_kernel<<<gatBlocks, blk, 0, stream>>>(cat01_b, l1_att, l1_bias,
                                               bufH, bufH, bufH_b, offsets, srcs, N);
    // layer 2 (H=1) + residual projection
    gemm_mfma<<<dim3(mtiles, 128 / 64), blk, 0, stream>>>(bufH_b, wCat2, bc2, nullptr, cat2_b, N, 128, HC);
    gemm_mfma<<<dim3(mtiles, 64 / 64), blk, 0, stream>>>(bufH_b, wRes, nullptr, bufRes, nullptr, N, C, HC);
    gat1_kernel<<<gatBlocks, blk, 0, stream>>>(cat2_b, l2_att, l2_bias,
                                               bufRes, out, offsets, srcs, N);
    // pooling + head
    pool_kernel<<<(N + 127) / 128, 64, 0, stream>>>(out, batch, pooled, N);
    head_kernel<<<1, 256, 0, stream>>>(pooled, d1_w, d1_b, bn_g, bn_b, bn_m, bn_v,
                                       d2_w, d2_b, out + (size_t)N * C);
}